// Round 15
// baseline (226.993 us; speedup 1.0000x reference)
//
#include <hip/hip_runtime.h>

#define C_IN   8
#define CH     8
#define Hh     128
#define Ww     192
#define HW     (Hh*Ww)
#define NINST  128
#define NPAR   169
#define OH     256
#define OW     384
#define B      8             // owned source rows per block
#define NRG    (Hh/B)        // 16 row groups

typedef float f32x2 __attribute__((ext_vector_type(2)));
typedef float f32x4 __attribute__((ext_vector_type(4)));

__device__ __forceinline__ f32x2 pk2(float s) { f32x2 r; r.x = s; r.y = s; return r; }

// Packed LDS weights (16B-aligned, 192 floats) — R11/R14 proven layout:
//   [0,96): w0 [8][12] | [96,160): w1 [8][8] | [160,168): w2[8]
//   [168,176): b0 | [176,184): b1 | [184]: b2
//
// Output mapping: block rg computes source rows [r0, r0+8] (9 rows, 12.5%
// halo redundancy vs 25% at B=4), writes out rows [2r0+2, 2r0+18);
// rg==0 adds rows {0,1}; rg==15 clips rows 256,257.
//
// Codegen lessons: launch_bounds w>=4 caps VGPR<=64 -> spills (R6/R7/R13);
// w=3 (cap ~85) is the only clean point. fp32 pk math is half-rate (R11 null)
// -> VALU cycles fixed by FMA count; R15 cuts FMA 10% (halo) + setup 2x.

__global__ __launch_bounds__(192, 3)
void fused_maskhead_kernel(const float* __restrict__ feats,
                           const float* __restrict__ params,
                           const float* __restrict__ locs,
                           const int* __restrict__ im_inds,
                           const int* __restrict__ fpn,
                           float* __restrict__ out)
{
    __shared__ __align__(16) float sw[192];
    __shared__ float sb[2][9];      // boundary z for cols 63, 127

    const int rg   = blockIdx.x;    // 0..15
    const int inst = blockIdx.y;    // 0..127
    const int x    = threadIdx.x;   // 0..191 — one column per thread
    const int r0   = rg * B;        // <= 120: rows r0..r0+7 never clamp

    // stage + repack params (coalesced global read, remapped LDS write)
    if (x < NPAR) {
        const int r = x;
        int dst;
        if (r < 80)       { const int o = r / 10; dst = o * 12 + (r - o * 10); }
        else if (r < 144) dst = 96  + (r - 80);
        else if (r < 152) dst = 160 + (r - 144);
        else if (r < 160) dst = 168 + (r - 152);
        else if (r < 168) dst = 176 + (r - 160);
        else              dst = 184;
        sw[dst] = params[inst * NPAR + r];
    }

    const float ixv = locs[inst * 2 + 0];
    const float iyv = locs[inst * 2 + 1];
    const float inv_soi = 1.0f / (float)(64 << fpn[inst]);
    const float rx = (ixv - (float)(x * 8 + 4)) * inv_soi;
    const float* fb = feats + (size_t)im_inds[inst] * (C_IN * HW) + x;

    __syncthreads();

    // 4 rows {ra..ra+3} -> logits (pk-paired, L3 folded into L2)
    auto mlp4 = [&](int ra) -> f32x4 {
        f32x2 ry2[2];
        ry2[0].x = (iyv - (float)((ra + 0) * 8 + 4)) * inv_soi;
        ry2[0].y = (iyv - (float)((ra + 1) * 8 + 4)) * inv_soi;
        ry2[1].x = (iyv - (float)((ra + 2) * 8 + 4)) * inv_soi;
        ry2[1].y = (iyv - (float)((ra + 3) * 8 + 4)) * inv_soi;

        f32x2 f2[2][C_IN];
        #pragma unroll
        for (int c = 0; c < C_IN; ++c) {
            const float* fc = fb + c * HW;
            f2[0][c].x = fc[(ra + 0) * Ww];
            f2[0][c].y = fc[(ra + 1) * Ww];
            f2[1][c].x = fc[(ra + 2) * Ww];
            f2[1][c].y = fc[(ra + 3) * Ww];
        }

        f32x2 h1a[CH], h1b[CH];
        #pragma unroll
        for (int o = 0; o < CH; ++o) {
            const f32x4 wa = *(const f32x4*)(sw + o * 12 + 0);
            const f32x4 wb = *(const f32x4*)(sw + o * 12 + 4);
            const f32x4 wc = *(const f32x4*)(sw + o * 12 + 8);   // .z/.w pad
            const float c0 = fmaf(wa.x, rx, sw[168 + o]);
            const float wv[C_IN] = {wa.z, wa.w, wb.x, wb.y, wb.z, wb.w, wc.x, wc.y};

            f32x2 a0 = pk2(wa.y) * ry2[0] + pk2(c0);
            f32x2 a1 = pk2(wa.y) * ry2[1] + pk2(c0);
            #pragma unroll
            for (int c = 0; c < C_IN; ++c) {
                a0 = pk2(wv[c]) * f2[0][c] + a0;
                a1 = pk2(wv[c]) * f2[1][c] + a1;
            }
            h1a[o].x = fmaxf(a0.x, 0.0f);  h1a[o].y = fmaxf(a0.y, 0.0f);
            h1b[o].x = fmaxf(a1.x, 0.0f);  h1b[o].y = fmaxf(a1.y, 0.0f);
        }

        f32x2 z01 = pk2(sw[184]);
        f32x2 z23 = pk2(sw[184]);
        #pragma unroll
        for (int o = 0; o < CH; ++o) {
            const f32x4 wa = *(const f32x4*)(sw + 96 + o * 8 + 0);
            const f32x4 wb = *(const f32x4*)(sw + 96 + o * 8 + 4);
            const float bo = sw[176 + o];
            const float w2o = sw[160 + o];
            const float wv[CH] = {wa.x, wa.y, wa.z, wa.w, wb.x, wb.y, wb.z, wb.w};

            f32x2 a0 = pk2(bo);
            f32x2 a1 = pk2(bo);
            #pragma unroll
            for (int c = 0; c < CH; ++c) {
                a0 = pk2(wv[c]) * h1a[c] + a0;
                a1 = pk2(wv[c]) * h1b[c] + a1;
            }
            f32x2 t0, t1;
            t0.x = fmaxf(a0.x, 0.0f);  t0.y = fmaxf(a0.y, 0.0f);
            t1.x = fmaxf(a1.x, 0.0f);  t1.y = fmaxf(a1.y, 0.0f);
            z01 = pk2(w2o) * t0 + z01;
            z23 = pk2(w2o) * t1 + z23;
        }
        f32x4 r;
        r.x = z01.x; r.y = z01.y; r.z = z23.x; r.w = z23.y;
        return r;
    };

    const f32x4 zA = mlp4(r0);
    asm volatile("" ::: "memory");       // keep phase register sets disjoint
    const f32x4 zB = mlp4(r0 + 4);
    asm volatile("" ::: "memory");

    // halo row r0+8 (clamped), scalar path
    float z8;
    {
        const int r8 = min(r0 + 8, Hh - 1);
        const float ry = (iyv - (float)(r8 * 8 + 4)) * inv_soi;
        float f4[C_IN];
        #pragma unroll
        for (int c = 0; c < C_IN; ++c) f4[c] = fb[c * HW + r8 * Ww];

        float h1s[CH];
        #pragma unroll
        for (int o = 0; o < CH; ++o) {
            const f32x4 wa = *(const f32x4*)(sw + o * 12 + 0);
            const f32x4 wb = *(const f32x4*)(sw + o * 12 + 4);
            const f32x4 wc = *(const f32x4*)(sw + o * 12 + 8);
            const float wv[C_IN] = {wa.z, wa.w, wb.x, wb.y, wb.z, wb.w, wc.x, wc.y};
            float a = fmaf(wa.x, rx, sw[168 + o]);
            a = fmaf(wa.y, ry, a);
            #pragma unroll
            for (int c = 0; c < C_IN; ++c) a = fmaf(wv[c], f4[c], a);
            h1s[o] = fmaxf(a, 0.0f);
        }
        z8 = sw[184];
        #pragma unroll
        for (int o = 0; o < CH; ++o) {
            const f32x4 wa = *(const f32x4*)(sw + 96 + o * 8 + 0);
            const f32x4 wb = *(const f32x4*)(sw + 96 + o * 8 + 4);
            const float wv[CH] = {wa.x, wa.y, wa.z, wa.w, wb.x, wb.y, wb.z, wb.w};
            float a = sw[176 + o];
            #pragma unroll
            for (int c = 0; c < CH; ++c) a = fmaf(wv[c], h1s[c], a);
            z8 = fmaf(sw[160 + o], fmaxf(a, 0.0f), z8);
        }
    }

    float z[9] = {zA.x, zA.y, zA.z, zA.w, zB.x, zB.y, zB.z, zB.w, z8};

    // boundary cols for the cross-wave shuffle (cols 64,128 need 63,127)
    if (x == 63) {
        #pragma unroll
        for (int t = 0; t < 9; ++t) sb[0][t] = z[t];
    }
    if (x == 127) {
        #pragma unroll
        for (int t = 0; t < 9; ++t) sb[1][t] = z[t];
    }
    __syncthreads();

    float zp[9];
    #pragma unroll
    for (int t = 0; t < 9; ++t) zp[t] = __shfl_up(z[t], 1);   // lane0 keeps own == col-0 clamp
    if (x == 64) {
        #pragma unroll
        for (int t = 0; t < 9; ++t) zp[t] = sb[0][t];
    }
    if (x == 128) {
        #pragma unroll
        for (int t = 0; t < 9; ++t) zp[t] = sb[1][t];
    }

    // out rows oy = 2r0+2+j, j=0..15:  rm[2t] = 0.5(z[t]+z[t+1]), rm[2t+1] = z[t+1]
    f32x2* outf2 = (f32x2*)out;
    const size_t obase = ((size_t)inst * OH + (2 * r0 + 2)) * (OW / 2) + x;
    #pragma unroll
    for (int t = 0; t < 8; ++t) {
        if (rg < NRG - 1 || 2 * t < 14) {          // rg==15 clips rows 256,257
            const float mid  = 0.5f * (z[t] + z[t + 1]);
            const float midp = 0.5f * (zp[t] + zp[t + 1]);
            f32x2 v0, v1;
            v0.x = 0.5f * (midp + mid);
            v0.y = mid;
            v1.x = 0.5f * (zp[t + 1] + z[t + 1]);
            v1.y = z[t + 1];
            outf2[obase + (size_t)(2 * t)     * (OW / 2)] = v0;
            outf2[obase + (size_t)(2 * t + 1) * (OW / 2)] = v1;
        }
    }
    if (rg == 0) {                                  // out rows 0,1 (row-mix at ay=0)
        f32x2 v;
        v.x = 0.5f * (zp[0] + z[0]);
        v.y = z[0];
        const size_t e = (size_t)inst * OH * (OW / 2) + x;
        outf2[e] = v;
        outf2[e + (OW / 2)] = v;
    }
}

extern "C" void kernel_launch(void* const* d_in, const int* in_sizes, int n_in,
                              void* d_out, int out_size, void* d_ws, size_t ws_size,
                              hipStream_t stream) {
    const float* feats  = (const float*)d_in[0];
    const float* params = (const float*)d_in[1];
    const float* locs   = (const float*)d_in[2];
    const int*   im     = (const int*)d_in[3];
    const int*   fpn    = (const int*)d_in[4];
    float* out = (float*)d_out;

    dim3 grid(NRG, NINST);   // 16 x 128 = 2048 blocks
    fused_maskhead_kernel<<<grid, 192, 0, stream>>>(feats, params, locs, im, fpn, out);
}

// Round 16
// 29.738 us; speedup vs baseline: 7.6331x; 7.6331x over previous
//
#include <hip/hip_runtime.h>

#define C_IN   8
#define CH     8
#define Hh     128
#define Ww     192
#define HW     (Hh*Ww)
#define NINST  128
#define NPAR   169
#define OH     256
#define OW     384
#define B      8             // owned source rows per block
#define RT     (B+1)         // computed rows incl. bottom halo
#define NRG    (Hh/B)        // 16 row groups

typedef float f32x2 __attribute__((ext_vector_type(2)));
typedef float f32x4 __attribute__((ext_vector_type(4)));

__device__ __forceinline__ f32x2 pk2(float s) { f32x2 r; r.x = s; r.y = s; return r; }

// Packed LDS weights (16B-aligned, 192 floats) — R11/R14 proven layout:
//   [0,96): w0 [8][12] | [96,160): w1 [8][8] | [160,168): w2[8]
//   [168,176): b0 | [176,184): b1 | [184]: b2
//
// Output mapping: block rg computes source rows [r0, r0+8] (12.5% halo
// redundancy), writes out rows [2r0+2, 2r0+18); rg==0 adds {0,1};
// rg==15 clips 256,257.
//
// Codegen lessons: w>=4 caps VGPR<=64 -> spill (R6/R7/R13); w=3 cap ~85.
// Any structure persisting z-state across MLP phases spills (R8/R15).
// R16: each phase writes its 4 logits straight to the LDS sl tile ->
// zero cross-phase register state; per-phase demand = R11's proven ~70.

__global__ __launch_bounds__(192, 3)
void fused_maskhead_kernel(const float* __restrict__ feats,
                           const float* __restrict__ params,
                           const float* __restrict__ locs,
                           const int* __restrict__ im_inds,
                           const int* __restrict__ fpn,
                           float* __restrict__ out)
{
    __shared__ __align__(16) float sw[192];
    __shared__ float sl[RT][Ww];    // 9*192*4 = 6912 B

    const int rg   = blockIdx.x;    // 0..15
    const int inst = blockIdx.y;    // 0..127
    const int x    = threadIdx.x;   // 0..191 — one column per thread
    const int r0   = rg * B;        // <= 120: rows r0..r0+7 never clamp

    // stage + repack params (coalesced global read, remapped LDS write)
    if (x < NPAR) {
        const int r = x;
        int dst;
        if (r < 80)       { const int o = r / 10; dst = o * 12 + (r - o * 10); }
        else if (r < 144) dst = 96  + (r - 80);
        else if (r < 152) dst = 160 + (r - 144);
        else if (r < 160) dst = 168 + (r - 152);
        else if (r < 168) dst = 176 + (r - 160);
        else              dst = 184;
        sw[dst] = params[inst * NPAR + r];
    }

    const float ixv = locs[inst * 2 + 0];
    const float iyv = locs[inst * 2 + 1];
    const float inv_soi = 1.0f / (float)(64 << fpn[inst]);
    const float rx = (ixv - (float)(x * 8 + 4)) * inv_soi;
    const float* fb = feats + (size_t)im_inds[inst] * (C_IN * HW) + x;

    __syncthreads();

    // 4 rows {ra..ra+3} -> logits straight into sl (pk-paired, L3 folded)
    auto mlp4 = [&](int ra) {
        f32x2 ry2[2];
        ry2[0].x = (iyv - (float)((ra + 0) * 8 + 4)) * inv_soi;
        ry2[0].y = (iyv - (float)((ra + 1) * 8 + 4)) * inv_soi;
        ry2[1].x = (iyv - (float)((ra + 2) * 8 + 4)) * inv_soi;
        ry2[1].y = (iyv - (float)((ra + 3) * 8 + 4)) * inv_soi;

        f32x2 f2[2][C_IN];
        #pragma unroll
        for (int c = 0; c < C_IN; ++c) {
            const float* fc = fb + c * HW;
            f2[0][c].x = fc[(ra + 0) * Ww];
            f2[0][c].y = fc[(ra + 1) * Ww];
            f2[1][c].x = fc[(ra + 2) * Ww];
            f2[1][c].y = fc[(ra + 3) * Ww];
        }

        f32x2 h1a[CH], h1b[CH];
        #pragma unroll
        for (int o = 0; o < CH; ++o) {
            const f32x4 wa = *(const f32x4*)(sw + o * 12 + 0);
            const f32x4 wb = *(const f32x4*)(sw + o * 12 + 4);
            const f32x4 wc = *(const f32x4*)(sw + o * 12 + 8);   // .z/.w pad
            const float c0 = fmaf(wa.x, rx, sw[168 + o]);
            const float wv[C_IN] = {wa.z, wa.w, wb.x, wb.y, wb.z, wb.w, wc.x, wc.y};

            f32x2 a0 = pk2(wa.y) * ry2[0] + pk2(c0);
            f32x2 a1 = pk2(wa.y) * ry2[1] + pk2(c0);
            #pragma unroll
            for (int c = 0; c < C_IN; ++c) {
                a0 = pk2(wv[c]) * f2[0][c] + a0;
                a1 = pk2(wv[c]) * f2[1][c] + a1;
            }
            h1a[o].x = fmaxf(a0.x, 0.0f);  h1a[o].y = fmaxf(a0.y, 0.0f);
            h1b[o].x = fmaxf(a1.x, 0.0f);  h1b[o].y = fmaxf(a1.y, 0.0f);
        }

        f32x2 z01 = pk2(sw[184]);
        f32x2 z23 = pk2(sw[184]);
        #pragma unroll
        for (int o = 0; o < CH; ++o) {
            const f32x4 wa = *(const f32x4*)(sw + 96 + o * 8 + 0);
            const f32x4 wb = *(const f32x4*)(sw + 96 + o * 8 + 4);
            const float bo = sw[176 + o];
            const float w2o = sw[160 + o];
            const float wv[CH] = {wa.x, wa.y, wa.z, wa.w, wb.x, wb.y, wb.z, wb.w};

            f32x2 a0 = pk2(bo);
            f32x2 a1 = pk2(bo);
            #pragma unroll
            for (int c = 0; c < CH; ++c) {
                a0 = pk2(wv[c]) * h1a[c] + a0;
                a1 = pk2(wv[c]) * h1b[c] + a1;
            }
            f32x2 t0, t1;
            t0.x = fmaxf(a0.x, 0.0f);  t0.y = fmaxf(a0.y, 0.0f);
            t1.x = fmaxf(a1.x, 0.0f);  t1.y = fmaxf(a1.y, 0.0f);
            z01 = pk2(w2o) * t0 + z01;
            z23 = pk2(w2o) * t1 + z23;
        }
        const int base = ra - r0;
        sl[base + 0][x] = z01.x;
        sl[base + 1][x] = z01.y;
        sl[base + 2][x] = z23.x;
        sl[base + 3][x] = z23.y;
    };

    mlp4(r0);
    asm volatile("" ::: "memory");       // phases sequential, no reg overlap
    mlp4(r0 + 4);
    asm volatile("" ::: "memory");

    // halo row r0+8 (clamped), scalar path -> sl[8]
    {
        const int r8 = min(r0 + 8, Hh - 1);
        const float ry = (iyv - (float)(r8 * 8 + 4)) * inv_soi;
        float f4[C_IN];
        #pragma unroll
        for (int c = 0; c < C_IN; ++c) f4[c] = fb[c * HW + r8 * Ww];

        float h1s[CH];
        #pragma unroll
        for (int o = 0; o < CH; ++o) {
            const f32x4 wa = *(const f32x4*)(sw + o * 12 + 0);
            const f32x4 wb = *(const f32x4*)(sw + o * 12 + 4);
            const f32x4 wc = *(const f32x4*)(sw + o * 12 + 8);
            const float wv[C_IN] = {wa.z, wa.w, wb.x, wb.y, wb.z, wb.w, wc.x, wc.y};
            float a = fmaf(wa.x, rx, sw[168 + o]);
            a = fmaf(wa.y, ry, a);
            #pragma unroll
            for (int c = 0; c < C_IN; ++c) a = fmaf(wv[c], f4[c], a);
            h1s[o] = fmaxf(a, 0.0f);
        }
        float z8 = sw[184];
        #pragma unroll
        for (int o = 0; o < CH; ++o) {
            const f32x4 wa = *(const f32x4*)(sw + 96 + o * 8 + 0);
            const f32x4 wb = *(const f32x4*)(sw + 96 + o * 8 + 4);
            const float wv[CH] = {wa.x, wa.y, wa.z, wa.w, wb.x, wb.y, wb.z, wb.w};
            float a = sw[176 + o];
            #pragma unroll
            for (int c = 0; c < CH; ++c) a = fmaf(wv[c], h1s[c], a);
            z8 = fmaf(sw[160 + o], fmaxf(a, 0.0f), z8);
        }
        sl[8][x] = z8;
    }

    __syncthreads();

    // ---- 2x aligned bilinear from LDS tile (R9-proven epilogue)
    f32x2* outf2 = (f32x2*)out;
    const int xm1 = max(x - 1, 0);
    const int jlo = (rg == 0) ? -2 : 0;
    const int jhi = (rg == NRG - 1) ? 2 * B - 2 : 2 * B;

    #pragma unroll 4
    for (int jj = jlo; jj < jhi; ++jj) {
        const int oy  = 2 * r0 + 2 + jj;
        const int ay  = max(oy - 1, 0);
        const int y0l = (ay >> 1) - r0;            // 0..B
        const int y1l = min(y0l + 1, B);           // clamp only when fy==0
        const float fy = (ay & 1) ? 0.5f : 0.0f;

        const float t01 = sl[y0l][x];
        const float t00 = sl[y0l][xm1];
        const float t11 = sl[y1l][x];
        const float t10 = sl[y1l][xm1];

        const float rma = fmaf(fy, t10 - t00, t00);
        const float rmb = fmaf(fy, t11 - t01, t01);

        f32x2 v;
        v.x = 0.5f * (rma + rmb);
        v.y = rmb;
        outf2[((size_t)inst * OH + oy) * (OW / 2) + x] = v;
    }
}

extern "C" void kernel_launch(void* const* d_in, const int* in_sizes, int n_in,
                              void* d_out, int out_size, void* d_ws, size_t ws_size,
                              hipStream_t stream) {
    const float* feats  = (const float*)d_in[0];
    const float* params = (const float*)d_in[1];
    const float* locs   = (const float*)d_in[2];
    const int*   im     = (const int*)d_in[3];
    const int*   fpn    = (const int*)d_in[4];
    float* out = (float*)d_out;

    dim3 grid(NRG, NINST);   // 16 x 128 = 2048 blocks
    fused_maskhead_kernel<<<grid, 192, 0, stream>>>(feats, params, locs, im, fpn, out);
}